// Round 5
// baseline (109.334 us; speedup 1.0000x reference)
//
#include <hip/hip_runtime.h>

#define NCH   1024   // IN_CH
#define ZDIM  128
#define NZ    1024   // FEAT*FEAT
#define KOUT  72     // OUT_CH * F_SIZE * F_SIZE

typedef float f4 __attribute__((ext_vector_type(4)));

__device__ __forceinline__ float dot4(f4 a, f4 b) {
    return a.x * b.x + a.y * b.y + a.z * b.z + a.w * b.w;
}

// 512 threads = 8 waves; wave w owns d-rows [w*16, w*16+16).
// Main loop has NO cross-lane ops: per-lane partials go to per-wave LDS,
// reduced once in a short epilogue. __launch_bounds__(512,8) keeps VGPR<=64
// so 4 blocks/CU = 32 waves/CU.
__global__ __launch_bounds__(512, 8) void hyper_fused_kernel(
    const float* __restrict__ z,      // (NCH, NZ)
    const float* __restrict__ W_in,   // (NCH, ZDIM, NZ)
    const float* __restrict__ b_in,   // (NCH, ZDIM)
    const float* __restrict__ W_out,  // (KOUT, ZDIM)
    const float* __restrict__ b_out,  // (KOUT)
    float* __restrict__ out)          // (8, NCH, 3, 3) flat
{
    __shared__ float P[8][16][64];   // per-wave partial sums, 32 KB
    __shared__ float as[ZDIM];       // hidden activation a[c,:]

    const int c    = blockIdx.x;
    const int tid  = threadIdx.x;
    const int lane = tid & 63;
    const int wave = tid >> 6;

    // ---- register-cache this lane's slice of x[c] ----
    const f4* zp = (const f4*)(z + (size_t)c * NZ);
    const f4 xv0 = zp[lane];
    const f4 xv1 = zp[lane + 64];
    const f4 xv2 = zp[lane + 128];
    const f4 xv3 = zp[lane + 192];

    const f4* Wc = (const f4*)(W_in + (size_t)c * ZDIM * NZ);
    float (* __restrict__ Pw)[64] = P[wave];

    // ---- stage 1 main loop: pure load -> FMA -> ds_write (no cross-lane) ----
    for (int dd = 0; dd < 16; dd += 2) {
        const int d0 = wave * 16 + dd;
        const f4* r0 = Wc + (size_t)d0 * (NZ / 4) + lane;
        const f4* r1 = r0 + (NZ / 4);

        const f4 a0 = __builtin_nontemporal_load(r0);
        const f4 a1 = __builtin_nontemporal_load(r0 + 64);
        const f4 a2 = __builtin_nontemporal_load(r0 + 128);
        const f4 a3 = __builtin_nontemporal_load(r0 + 192);
        const f4 b0 = __builtin_nontemporal_load(r1);
        const f4 b1 = __builtin_nontemporal_load(r1 + 64);
        const f4 b2 = __builtin_nontemporal_load(r1 + 128);
        const f4 b3 = __builtin_nontemporal_load(r1 + 192);

        float s0 = dot4(a0, xv0) + dot4(a1, xv1) + dot4(a2, xv2) + dot4(a3, xv3);
        float s1 = dot4(b0, xv0) + dot4(b1, xv1) + dot4(b2, xv2) + dot4(b3, xv3);

        // swizzled column so write AND epilogue read are 2-way (free)
        Pw[dd    ][(lane + 4 * dd      ) & 63] = s0;
        Pw[dd + 1][(lane + 4 * (dd + 1)) & 63] = s1;
    }

    // ---- wave-local epilogue: 4 lanes per row, 16 partials each ----
    {
        const int r = lane >> 2;   // 0..15 : local row
        const int j = lane & 3;    // 0..3  : sub-reducer
        float u = 0.f;
        #pragma unroll
        for (int k = 0; k < 16; ++k)
            u += Pw[r][(j + 4 * k + 4 * r) & 63];   // partial from lane (j+4k)
        u += __shfl_xor(u, 1, 64);
        u += __shfl_xor(u, 2, 64);
        if (j == 0) {
            const int d = wave * 16 + r;
            as[d] = u + b_in[c * ZDIM + d];
        }
    }
    __syncthreads();

    // ---- stage 2: k[c,t] = a . W_out[t,:] + b_out[t], transposed store ----
    if (tid < KOUT) {
        const f4* wr = (const f4*)(W_out + tid * ZDIM);
        const f4* av = (const f4*)as;
        float sum = 0.f;
        #pragma unroll
        for (int jj = 0; jj < ZDIM / 4; ++jj)
            sum += dot4(wr[jj], av[jj]);
        sum += b_out[tid];
        const int o = tid / 9;
        const int rr = tid % 9;
        out[(size_t)o * (NCH * 9) + (size_t)c * 9 + rr] = sum;
    }
}

extern "C" void kernel_launch(void* const* d_in, const int* in_sizes, int n_in,
                              void* d_out, int out_size, void* d_ws, size_t ws_size,
                              hipStream_t stream) {
    const float* z     = (const float*)d_in[0];
    const float* W_in  = (const float*)d_in[1];
    const float* b_in  = (const float*)d_in[2];
    const float* W_out = (const float*)d_in[3];
    const float* b_out = (const float*)d_in[4];
    float* out = (float*)d_out;

    hyper_fused_kernel<<<NCH, 512, 0, stream>>>(z, W_in, b_in, W_out, b_out, out);
}

// Round 6
// 86.117 us; speedup vs baseline: 1.2696x; 1.2696x over previous
//
#include <hip/hip_runtime.h>

#define NCH   1024   // IN_CH
#define ZDIM  128
#define NZ    1024   // FEAT*FEAT
#define KOUT  72     // OUT_CH * F_SIZE * F_SIZE

typedef float f4 __attribute__((ext_vector_type(4)));

__device__ __forceinline__ float dot4(f4 a, f4 b) {
    return a.x * b.x + a.y * b.y + a.z * b.z + a.w * b.w;
}

// 512 threads = 8 waves. Row map: iteration it, wave w -> rows (it*16 + 2w, +1).
// All 8 waves read ADJACENT row-pairs, so the block forms one quasi-sequential
// 64KB moving front through its 512KB W_in slice (DRAM page locality), instead
// of 8 cursors 64KB apart. __launch_bounds__(512,8): VGPR<=64 -> 32 waves/CU.
__global__ __launch_bounds__(512, 8) void hyper_fused_kernel(
    const float* __restrict__ z,      // (NCH, NZ)
    const float* __restrict__ W_in,   // (NCH, ZDIM, NZ)
    const float* __restrict__ b_in,   // (NCH, ZDIM)
    const float* __restrict__ W_out,  // (KOUT, ZDIM)
    const float* __restrict__ b_out,  // (KOUT)
    float* __restrict__ out)          // (8, NCH, 3, 3) flat
{
    __shared__ float as[ZDIM];   // hidden activation a[c,:]

    const int c    = blockIdx.x;
    const int tid  = threadIdx.x;
    const int lane = tid & 63;
    const int wave = tid >> 6;

    // ---- register-cache this lane's slice of x[c] ----
    const f4* zp = (const f4*)(z + (size_t)c * NZ);
    const f4 xv0 = zp[lane];
    const f4 xv1 = zp[lane + 64];
    const f4 xv2 = zp[lane + 128];
    const f4 xv3 = zp[lane + 192];

    const f4* Wc = (const f4*)(W_in + (size_t)c * ZDIM * NZ);
    const float* bc = b_in + c * ZDIM;

    // ---- stage 1: 8 iterations x 2 rows per wave ----
    for (int it = 0; it < 8; ++it) {
        const int d0 = it * 16 + wave * 2;
        const f4* r0 = Wc + (size_t)d0 * (NZ / 4) + lane;
        const f4* r1 = r0 + (NZ / 4);

        const f4 a0 = __builtin_nontemporal_load(r0);
        const f4 a1 = __builtin_nontemporal_load(r0 + 64);
        const f4 a2 = __builtin_nontemporal_load(r0 + 128);
        const f4 a3 = __builtin_nontemporal_load(r0 + 192);
        const f4 b0 = __builtin_nontemporal_load(r1);
        const f4 b1 = __builtin_nontemporal_load(r1 + 64);
        const f4 b2 = __builtin_nontemporal_load(r1 + 128);
        const f4 b3 = __builtin_nontemporal_load(r1 + 192);

        float s0 = dot4(a0, xv0) + dot4(a1, xv1) + dot4(a2, xv2) + dot4(a3, xv3);
        float s1 = dot4(b0, xv0) + dot4(b1, xv1) + dot4(b2, xv2) + dot4(b3, xv3);

        // paired reduce: 7 shuffles for 2 rows
        float t0 = s0 + __shfl_xor(s0, 32, 64);
        float t1 = s1 + __shfl_xor(s1, 32, 64);
        float u  = (lane < 32) ? t0 : t1;   // halves carry row d0 / row d0+1
        u += __shfl_xor(u, 16, 64);
        u += __shfl_xor(u, 8, 64);
        u += __shfl_xor(u, 4, 64);
        u += __shfl_xor(u, 2, 64);
        u += __shfl_xor(u, 1, 64);

        if (lane == 0)  as[d0]     = u + bc[d0];
        if (lane == 32) as[d0 + 1] = u + bc[d0 + 1];
    }
    __syncthreads();

    // ---- stage 2: k[c,t] = a . W_out[t,:] + b_out[t], transposed store ----
    if (tid < KOUT) {
        const f4* wr = (const f4*)(W_out + tid * ZDIM);
        const f4* av = (const f4*)as;
        float sum = 0.f;
        #pragma unroll
        for (int j = 0; j < ZDIM / 4; ++j)
            sum += dot4(wr[j], av[j]);
        sum += b_out[tid];
        const int o = tid / 9;
        const int r = tid % 9;
        out[(size_t)o * (NCH * 9) + (size_t)c * 9 + r] = sum;
    }
}

extern "C" void kernel_launch(void* const* d_in, const int* in_sizes, int n_in,
                              void* d_out, int out_size, void* d_ws, size_t ws_size,
                              hipStream_t stream) {
    const float* z     = (const float*)d_in[0];
    const float* W_in  = (const float*)d_in[1];
    const float* b_in  = (const float*)d_in[2];
    const float* W_out = (const float*)d_in[3];
    const float* b_out = (const float*)d_in[4];
    float* out = (float*)d_out;

    hyper_fused_kernel<<<NCH, 512, 0, stream>>>(z, W_in, b_in, W_out, b_out, out);
}